// Round 7
// baseline (256.869 us; speedup 1.0000x reference)
//
#include <hip/hip_runtime.h>
#include <hip/hip_bf16.h>

// Problem constants
#define P_TOTAL 16384      // H*W pixels
#define KN      16         // kernels per pixel
#define CK      144        // in_channel * kernel_size
#define BATCH   8
#define IMG     262144     // C*H*W
#define PATCH_H 160        // padded patch row length (halfwords); K padded 144->160

typedef __attribute__((ext_vector_type(8))) short bf16x8;   // MFMA A/B frag (4 VGPRs)
typedef __attribute__((ext_vector_type(4))) float f32x4;    // MFMA C/D frag

__device__ __forceinline__ short f2bf(float f) {
    __hip_bfloat16 h = __float2bfloat16(f);
    return *reinterpret_cast<short*>(&h);
}

// ---------- K0: transpose+quantize x[b][id] f32 -> xt[id][b] bf16 (4.19 MB) ----------
__global__ __launch_bounds__(256) void transpose_x_bf16(
    const float* __restrict__ x, float4* __restrict__ xt)
{
    const int i = blockIdx.x * 256 + threadIdx.x;
    union { short h[8]; float4 f4; } u;
#pragma unroll
    for (int b = 0; b < BATCH; ++b)
        u.h[b] = f2bf(x[(size_t)b * IMG + i]);
    xt[i] = u.f4;
}

// ---------- K1: gather-only. xt is the only L2-reuse tenant -> high hit rate ----------
// Writes patches[p][b(8)][c(160)] bf16, zero-padded c=144..159, in MFMA-A layout.
__global__ __launch_bounds__(256) void gather_patches(
    const float4* __restrict__ xt,      // bf16 [IMG][8]
    const int*    __restrict__ hidx,    // [P][CK]
    unsigned short* __restrict__ patches)
{
    const int t    = threadIdx.x;
    const int wv   = t >> 6;
    const int lane = t & 63;
    const int bid  = blockIdx.x;
    const int p    = (bid & 7) * (P_TOTAL / 8) + (bid >> 3) * 4 + wv;

    const int* hp = hidx + p * CK;
    unsigned short* pp = patches + (size_t)p * BATCH * PATCH_H;

    union { unsigned short h[8]; float4 f4; } u0, u1, u2;
    u0.f4 = xt[hp[lane]];
    u1.f4 = xt[hp[lane + 64]];
    const bool tail = lane < (CK - 128);          // lanes 0..15 -> c=128..143
    if (tail) u2.f4 = xt[hp[lane + 128]];

    // b16 stores: 64 lanes x 2B contiguous = 2 full lines per instr
#pragma unroll
    for (int b = 0; b < BATCH; ++b) pp[b * PATCH_H + lane]       = u0.h[b];
#pragma unroll
    for (int b = 0; b < BATCH; ++b) pp[b * PATCH_H + lane + 64]  = u1.h[b];
    if (tail) {
#pragma unroll
        for (int b = 0; b < BATCH; ++b) pp[b * PATCH_H + lane + 128] = u2.h[b];
    } else if (lane < 32) {                        // lanes 16..31 -> zero pad c=144..159
#pragma unroll
        for (int b = 0; b < BATCH; ++b) pp[b * PATCH_H + lane + 128] = 0;
    }
}

// ---------- K2: pure-streaming GEMM. No LDS, no barrier, no random access ----------
// One wave per pixel: D[b16pad][k16] = A(patches) x B(W^T), 5x mfma_f32_16x16x32_bf16.
__global__ __launch_bounds__(256) void gemm_mfma(
    const unsigned short* __restrict__ patches,  // [P][8][160] bf16
    const float* __restrict__ w,                 // [P][KN][CK] f32
    float* __restrict__ out)                     // [B][KN][P] f32
{
    const int t    = threadIdx.x;
    const int wv   = t >> 6;
    const int lane = t & 63;
    const int bid  = blockIdx.x;
    const int p    = (bid & 7) * (P_TOTAL / 8) + (bid >> 3) * 4 + wv;

    const int n    = lane & 15;      // output k; A-row selector
    const int q    = lane >> 4;      // K-quad
    const int arow = n & 7;          // rows 8-15 broadcast rows 0-7 (dups discarded)
    const unsigned short* ap = patches + (size_t)p * BATCH * PATCH_H + (size_t)arow * PATCH_H;
    const float* wp = w + (size_t)p * (KN * CK) + (size_t)n * CK;

    f32x4 acc = {0.f, 0.f, 0.f, 0.f};
#pragma unroll
    for (int s = 0; s < 5; ++s) {
        const int c = 32 * s + 8 * q;
        bf16x8 a = *reinterpret_cast<const bf16x8*>(ap + c);  // 16B aligned (c%8==0, row 320B)
        bf16x8 b = {0, 0, 0, 0, 0, 0, 0, 0};
        if (c < CK) {                 // s=4,q>=2 -> zero frag (A reads pad zeros)
            const float4 f0 = *reinterpret_cast<const float4*>(wp + c);
            const float4 f1 = *reinterpret_cast<const float4*>(wp + c + 4);
            b[0] = f2bf(f0.x); b[1] = f2bf(f0.y); b[2] = f2bf(f0.z); b[3] = f2bf(f0.w);
            b[4] = f2bf(f1.x); b[5] = f2bf(f1.y); b[6] = f2bf(f1.z); b[7] = f2bf(f1.w);
        }
        acc = __builtin_amdgcn_mfma_f32_16x16x32_bf16(a, b, acc, 0, 0, 0);
    }

    // C/D: col=lane&15 (=k), row=q*4+i (=b); rows 8-15 duplicate rows 0-7
    if (lane < 32) {
#pragma unroll
        for (int i = 0; i < 4; ++i) {
            const int b = q * 4 + i;
            out[(size_t)b * (KN * P_TOTAL) + (size_t)n * P_TOTAL + p] = acc[i];
        }
    }
}

// ---------- fallback (tiny workspace): R2-style single kernel ----------
__global__ __launch_bounds__(256) void abc2d_fallback(
    const float* __restrict__ x, const float* __restrict__ w,
    const int* __restrict__ hidx, float* __restrict__ out)
{
    __shared__ float patch[CK * 12];
    const int bid = blockIdx.x;
    const int p   = (bid & 7) * (P_TOTAL / 8) + (bid >> 3);
    const int t   = threadIdx.x;
    const int* hp = hidx + p * CK;
    for (int j = t; j < CK * BATCH; j += 256) {
        const int c = j >> 3, b = j & 7;
        patch[c * 12 + b] = x[(size_t)hp[c] + (size_t)b * IMG];
    }
    __syncthreads();
    const int k = t >> 4, cs = t & 15;
    const float* wp = w + (size_t)p * (KN * CK) + (size_t)k * CK;
    float acc[BATCH];
#pragma unroll
    for (int b = 0; b < BATCH; ++b) acc[b] = 0.f;
#pragma unroll
    for (int i = 0; i < 9; ++i) {
        const int c = cs + 16 * i;
        const float wv = wp[c];
        const float* pr = &patch[c * 12];
#pragma unroll
        for (int b = 0; b < BATCH; ++b) acc[b] += wv * pr[b];
    }
#pragma unroll
    for (int b = 0; b < BATCH; ++b) {
        float v = acc[b];
        v += __shfl_xor(v, 1); v += __shfl_xor(v, 2);
        v += __shfl_xor(v, 4); v += __shfl_xor(v, 8);
        acc[b] = v;
    }
    if (cs == 0)
#pragma unroll
        for (int b = 0; b < BATCH; ++b)
            out[(size_t)b * (KN * P_TOTAL) + (size_t)k * P_TOTAL + p] = acc[b];
}

extern "C" void kernel_launch(void* const* d_in, const int* in_sizes, int n_in,
                              void* d_out, int out_size, void* d_ws, size_t ws_size,
                              hipStream_t stream) {
    const float* x    = (const float*)d_in[0];   // [8,16,128,128] f32
    const float* wts  = (const float*)d_in[1];   // [16384,16,144] f32
    const int*   hidx = (const int*)d_in[2];     // [16384,144] int32
    float* out = (float*)d_out;                  // [8,16,16384] f32

    const size_t xt_bytes    = (size_t)IMG * BATCH * sizeof(short);              // 4.19 MB
    const size_t patch_bytes = (size_t)P_TOTAL * BATCH * PATCH_H * sizeof(short); // 41.9 MB
    const size_t patch_off   = 8u << 20;                                          // 8 MB align

    if (ws_size >= patch_off + patch_bytes) {
        float4* xt = (float4*)d_ws;
        unsigned short* patches = (unsigned short*)((char*)d_ws + patch_off);
        transpose_x_bf16<<<IMG / 256, 256, 0, stream>>>(x, xt);
        gather_patches<<<P_TOTAL / 4, 256, 0, stream>>>(xt, hidx, patches);
        gemm_mfma<<<P_TOTAL / 4, 256, 0, stream>>>(patches, wts, out);
    } else {
        abc2d_fallback<<<P_TOTAL, 256, 0, stream>>>(x, wts, hidx, out);
    }
}